// Round 13
// baseline (116.494 us; speedup 1.0000x reference)
//
#include <hip/hip_runtime.h>
#include <stdint.h>

// Problem shape (fixed by reference setup_inputs): B=4096, L=2048.
#define LROW 2048
#define THREADS 256
#define NBINS 1024
#define BPT (NBINS / THREADS)   // 4 bins owned per thread
#define RUNROLL 6               // fixed predicated rank unroll; P(size>6)~6e-4

// Transposed hist layout: bin b -> [(b&3)*256 + (b>>2)] so thread-contiguous
// bin ownership is lane-stride-1 in the scan (fixed 16-way conflicts, r8).
__device__ __forceinline__ int swz(int b) {
    return ((b & (BPT - 1)) << 8) + (b >> 2);
}

// One block per row. Stable argsort of (masked -> +inf) keys; masked elements
// DROPPED (outputs past `valid` are pad).
//
// r8-r12 history: four different ordering back-ends ran at IDENTICAL 41.9us
// => not instruction-stream-bound; block-level latency with only ~4 blocks/CU
// resident (LDS 24.25KB). r13 change: split u64 keys into key32+idx16 ->
// LDS 20.3KB -> 8 blocks/CU (+33% concurrency). Ties resolved via idx16 only
// on key32 equality (rare but real; self-compare is tie-safe). Rank reads
// drop from b64 to b32.
//
// mask (jnp.bool_) is uploaded by the harness as int32.
__global__ __launch_bounds__(THREADS) void time_greedy_rank_kernel(
    const float* __restrict__ time,
    const int* __restrict__ mask,             // int32: nonzero = excluded
    const int* __restrict__ pad_value_p,
    int* __restrict__ pred,                   // [B, L] int32
    int* __restrict__ valid_out)              // [B]    int32
{
    __shared__ uint32_t key32[LROW];     // 8 KB: scattered sortable key bits
    __shared__ uint16_t idx16[LROW];     // 4 KB: scattered original indices
    __shared__ uint32_t hstart[NBINS];   // 4 KB: exclusive bucket starts
    __shared__ uint32_t hpos[NBINS];     // 4 KB: counts->pos; REUSED as u16 oidx
    __shared__ uint32_t wsum[4];

    uint16_t* oidx = (uint16_t*)hpos;    // aliases hpos after scatter is done

    const int row = blockIdx.x;
    const int tid = threadIdx.x;
    const int lane = tid & 63;
    const int wid = tid >> 6;

    // ---- init hpos (stride-1) ----
#pragma unroll
    for (int e = 0; e < BPT; ++e) hpos[tid + e * THREADS] = 0;
    __syncthreads();

    // ---- vectorized load + histogram of valid elements ----
    const float4* trow4 = (const float4*)(time + (size_t)row * LROW);
    const int4*   mrow4 = (const int4*)(mask + (size_t)row * LROW);

    uint32_t ukey[8];
    int      bkt[8];
    int      mval[8];
#pragma unroll
    for (int c = 0; c < 2; ++c) {
        const int v = tid + c * THREADS;
        const float4 tq = trow4[v];
        const int4   mq = mrow4[v];
        const float tf[4] = {tq.x, tq.y, tq.z, tq.w};
        const int   mf[4] = {mq.x, mq.y, mq.z, mq.w};
#pragma unroll
        for (int j = 0; j < 4; ++j) {
            const int e = c * 4 + j;
            const uint32_t fb = __float_as_uint(tf[j]);
            // order-preserving float->uint transform (general form)
            ukey[e] = fb ^ ((uint32_t)((int32_t)fb >> 31) | 0x80000000u);
            int b = (int)(tf[j] * (float)NBINS);   // monotone value bucketing
            b = (b < 0) ? 0 : ((b > NBINS - 1) ? NBINS - 1 : b);
            bkt[e] = b;
            mval[e] = mf[j];
            if (!mf[j]) atomicAdd(&hpos[swz(b)], 1u);
        }
    }
    __syncthreads();

    // ---- exclusive prefix sum over 1024 bins (thread t owns bins 4t..4t+3) ----
    uint32_t h[BPT];
    uint32_t lsum = 0;
#pragma unroll
    for (int e = 0; e < BPT; ++e) {
        h[e] = hpos[e * THREADS + tid];   // stride-1
        lsum += h[e];
    }
    uint32_t incl = lsum;                 // wave-inclusive scan
#pragma unroll
    for (int off = 1; off < 64; off <<= 1) {
        const uint32_t y = __shfl_up(incl, off, 64);
        if (lane >= off) incl += y;
    }
    if (lane == 63) wsum[wid] = incl;
    __syncthreads();
    uint32_t woff = 0, total = 0;
#pragma unroll
    for (int w = 0; w < 4; ++w) {
        const uint32_t s = wsum[w];
        if (w < wid) woff += s;
        total += s;
    }
    uint32_t run = woff + incl - lsum;    // exclusive prefix for this thread's bins
#pragma unroll
    for (int e = 0; e < BPT; ++e) {
        hstart[e * THREADS + tid] = run;  // exclusive start (preserved)
        hpos[e * THREADS + tid] = run;    // running position for scatter
        run += h[e];
    }
    __syncthreads();

    // ---- scatter valid elements into their bucket ranges ----
#pragma unroll
    for (int c = 0; c < 2; ++c) {
#pragma unroll
        for (int j = 0; j < 4; ++j) {
            const int e = c * 4 + j;
            if (!mval[e]) {
                const int i = 4 * tid + c * (4 * THREADS) + j;  // element index
                const uint32_t pos = atomicAdd(&hpos[swz(bkt[e])], 1u);
                key32[pos] = ukey[e];
                idx16[pos] = (uint16_t)i;
            }
        }
    }
    __syncthreads();
    // hpos now DEAD (bucket end b == hstart[b+1], or total for the last bin).
    // Its 4 KB are reused as the u16 rank-staging array oidx.

    const int vld = (int)total;

    // ---- prefetch all 8 (start, cap) pairs: independent pipelined reads ----
    uint32_t sarr[8], cap[8];
#pragma unroll
    for (int e = 0; e < 8; ++e) {
        const int b = bkt[e];
        const uint32_t s = hstart[swz(b)];
        const uint32_t en = (b == NBINS - 1) ? (uint32_t)vld
                                             : hstart[swz(b + 1)];
        sarr[e] = s;
        cap[e] = mval[e] ? 0u : (en - s);   // cap=0 disables masked slots
    }

    // ---- branch-free fixed-unroll rank (b32 + rare tie path) -> u16 stage ----
#pragma unroll
    for (int e = 0; e < 8; ++e) {
        const int c = e >> 2, j = e & 3;
        const int i = 4 * tid + c * (4 * THREADS) + j;   // element index
        const uint32_t my32 = ukey[e];
        const uint16_t myidx = (uint16_t)i;
        const uint32_t s = sarr[e], cz = cap[e];
        uint32_t rank = 0;
#pragma unroll
        for (uint32_t k = 0; k < RUNROLL; ++k) {
            if (k < cz) {
                const uint32_t kk = key32[s + k];
                rank += (kk < my32) ? 1u : 0u;
                // float-key tie (rare but must be exact; self gives +0)
                if (kk == my32) rank += (idx16[s + k] < myidx) ? 1u : 0u;
            }
        }
        for (uint32_t k = RUNROLL; k < cz; ++k) {             // rare tail
            const uint32_t kk = key32[s + k];
            rank += (kk < my32) ? 1u : 0u;
            if (kk == my32) rank += (idx16[s + k] < myidx) ? 1u : 0u;
        }
        if (cz) oidx[s + rank] = myidx;
    }
    __syncthreads();

    // ---- coalesced int4 emit, pad folded in ----
    const int pad = pad_value_p[0];
    int4* prow4 = (int4*)(pred + (size_t)row * LROW);
#pragma unroll
    for (int c = 0; c < 2; ++c) {
        const int v = tid + c * THREADS;
        const int base = 4 * v;
        int4 o;                              // 8B/lane u16 reads: 2-way, free
        o.x = (base + 0 < vld) ? (int)oidx[base + 0] : pad;
        o.y = (base + 1 < vld) ? (int)oidx[base + 1] : pad;
        o.z = (base + 2 < vld) ? (int)oidx[base + 2] : pad;
        o.w = (base + 3 < vld) ? (int)oidx[base + 3] : pad;
        prow4[v] = o;                        // 1 KB/wave coalesced store
    }
    if (tid == 0) valid_out[row] = vld;
}

extern "C" void kernel_launch(void* const* d_in, const int* in_sizes, int n_in,
                              void* d_out, int out_size, void* d_ws, size_t ws_size,
                              hipStream_t stream) {
    const float* time = (const float*)d_in[0];
    const int* mask = (const int*)d_in[1];
    const int* pad_value = (const int*)d_in[2];

    const int B = in_sizes[0] / LROW;

    // d_out layout: pred [B*L] int32, then valid [B] int32 (tuple concat order)
    int* pred = (int*)d_out;
    int* valid_out = pred + (size_t)B * LROW;

    time_greedy_rank_kernel<<<B, THREADS, 0, stream>>>(time, mask, pad_value,
                                                       pred, valid_out);
}

// Round 14
// 109.141 us; speedup vs baseline: 1.0674x; 1.0674x over previous
//
#include <hip/hip_runtime.h>
#include <stdint.h>

// Problem shape (fixed by reference setup_inputs): B=4096, L=2048.
#define LROW 2048
#define THREADS 512             // r14: 256->512. Halves per-thread phase work,
                                // 8 waves/block x 4 blocks/CU = 100% wave occ.
#define EPT (LROW / THREADS)    // 4 elements per thread
#define NBINS 1024
#define BPT (NBINS / THREADS)   // 2 bins owned per thread
#define RUNROLL 6               // fixed predicated rank unroll; P(size>6)~6e-4

// Transposed hist layout: bin b -> [(b&1)*512 + (b>>1)] so thread-contiguous
// bin ownership (thread t owns bins 2t,2t+1) is lane-stride-1 in the scan.
__device__ __forceinline__ int swz(int b) {
    return ((b & (BPT - 1)) << 9) + (b >> 1);
}

// One block per row. Stable argsort of (masked -> +inf) keys; masked elements
// DROPPED (outputs past `valid` are pad).
//
// History: r8-r12 four back-ends identical 41.9us (instruction mix is not the
// limiter); r13 higher occupancy via split keys REGRESSED to 50us (extra LDS
// traffic; concurrency doesn't fill the stall). Conclusion: per-block critical
// path bound. r14: halve the path by doubling threads (512), same u64-key
// algorithm/layout as r12.
//
// mask (jnp.bool_) is uploaded by the harness as int32.
__global__ __launch_bounds__(THREADS) void time_greedy_rank_kernel(
    const float* __restrict__ time,
    const int* __restrict__ mask,             // int32: nonzero = excluded
    const int* __restrict__ pad_value_p,
    int* __restrict__ pred,                   // [B, L] int32
    int* __restrict__ valid_out)              // [B]    int32
{
    __shared__ uint64_t keys[LROW];      // 16 KB: scattered composite keys
    __shared__ uint32_t hstart[NBINS];   // 4 KB: exclusive bucket starts
    __shared__ uint32_t hpos[NBINS];     // 4 KB: counts->pos; REUSED as u16 oidx
    __shared__ uint32_t wsum[8];         // per-wave scan totals (8 waves)

    uint16_t* oidx = (uint16_t*)hpos;    // aliases hpos after scatter is done

    const int row = blockIdx.x;
    const int tid = threadIdx.x;
    const int lane = tid & 63;
    const int wid = tid >> 6;

    // ---- init hpos (stride-1) ----
#pragma unroll
    for (int e = 0; e < BPT; ++e) hpos[tid + e * THREADS] = 0;
    __syncthreads();

    // ---- vectorized load + histogram of valid elements ----
    // Thread t covers elements 4t..4t+3 in one float4/int4 pair.
    const float4* trow4 = (const float4*)(time + (size_t)row * LROW);
    const int4*   mrow4 = (const int4*)(mask + (size_t)row * LROW);

    const float4 tq = trow4[tid];
    const int4   mq = mrow4[tid];
    const float tf[4] = {tq.x, tq.y, tq.z, tq.w};
    const int   mf[4] = {mq.x, mq.y, mq.z, mq.w};

    uint32_t ukey[EPT];
    int      bkt[EPT];
#pragma unroll
    for (int j = 0; j < EPT; ++j) {
        const uint32_t fb = __float_as_uint(tf[j]);
        // order-preserving float->uint transform (general form)
        ukey[j] = fb ^ ((uint32_t)((int32_t)fb >> 31) | 0x80000000u);
        int b = (int)(tf[j] * (float)NBINS);   // monotone value bucketing
        b = (b < 0) ? 0 : ((b > NBINS - 1) ? NBINS - 1 : b);
        bkt[j] = b;
        if (!mf[j]) atomicAdd(&hpos[swz(b)], 1u);
    }
    __syncthreads();

    // ---- exclusive prefix sum over 1024 bins (thread t owns bins 2t,2t+1) ----
    uint32_t h[BPT];
    uint32_t lsum = 0;
#pragma unroll
    for (int e = 0; e < BPT; ++e) {
        h[e] = hpos[e * THREADS + tid];   // stride-1
        lsum += h[e];
    }
    uint32_t incl = lsum;                 // wave-inclusive scan
#pragma unroll
    for (int off = 1; off < 64; off <<= 1) {
        const uint32_t y = __shfl_up(incl, off, 64);
        if (lane >= off) incl += y;
    }
    if (lane == 63) wsum[wid] = incl;
    __syncthreads();
    uint32_t woff = 0, total = 0;
#pragma unroll
    for (int w = 0; w < 8; ++w) {
        const uint32_t s = wsum[w];
        if (w < wid) woff += s;
        total += s;
    }
    uint32_t run = woff + incl - lsum;    // exclusive prefix for this thread's bins
#pragma unroll
    for (int e = 0; e < BPT; ++e) {
        hstart[e * THREADS + tid] = run;  // exclusive start (preserved)
        hpos[e * THREADS + tid] = run;    // running position for scatter
        run += h[e];
    }
    __syncthreads();

    // ---- scatter valid elements into their bucket ranges ----
#pragma unroll
    for (int j = 0; j < EPT; ++j) {
        if (!mf[j]) {
            const int i = 4 * tid + j;                     // element index
            const uint32_t pos = atomicAdd(&hpos[swz(bkt[j])], 1u);
            keys[pos] = ((uint64_t)ukey[j] << 32) | (uint32_t)i;
        }
    }
    __syncthreads();
    // hpos now DEAD (bucket end b == hstart[b+1], or total for the last bin).
    // Its 4 KB are reused as the u16 rank-staging array oidx.

    const int vld = (int)total;

    // ---- prefetch all (start, cap) pairs: independent pipelined reads ----
    uint32_t sarr[EPT], cap[EPT];
#pragma unroll
    for (int j = 0; j < EPT; ++j) {
        const int b = bkt[j];
        const uint32_t s = hstart[swz(b)];
        const uint32_t en = (b == NBINS - 1) ? (uint32_t)vld
                                             : hstart[swz(b + 1)];
        sarr[j] = s;
        cap[j] = mf[j] ? 0u : (en - s);   // cap=0 disables masked slots
    }

    // ---- branch-free fixed-unroll rank -> u16 LDS staging ----
#pragma unroll
    for (int j = 0; j < EPT; ++j) {
        const int i = 4 * tid + j;                         // element index
        const uint64_t my = ((uint64_t)ukey[j] << 32) | (uint32_t)i;
        const uint32_t s = sarr[j], cz = cap[j];
        uint32_t rank = 0;
#pragma unroll
        for (uint32_t k = 0; k < RUNROLL; ++k) {
            if (k < cz) rank += (keys[s + k] < my) ? 1u : 0u;  // predicated
        }
        for (uint32_t k = RUNROLL; k < cz; ++k)               // rare tail
            rank += (keys[s + k] < my) ? 1u : 0u;
        if (cz) oidx[s + rank] = (uint16_t)i;   // self excluded by strict <
    }
    __syncthreads();

    // ---- coalesced int4 emit, pad folded in ----
    const int pad = pad_value_p[0];
    int4* prow4 = (int4*)(pred + (size_t)row * LROW);
    {
        const int base = 4 * tid;
        int4 o;                              // 8B/lane u16 reads: 2-way, free
        o.x = (base + 0 < vld) ? (int)oidx[base + 0] : pad;
        o.y = (base + 1 < vld) ? (int)oidx[base + 1] : pad;
        o.z = (base + 2 < vld) ? (int)oidx[base + 2] : pad;
        o.w = (base + 3 < vld) ? (int)oidx[base + 3] : pad;
        prow4[tid] = o;                      // 1 KB/wave coalesced store
    }
    if (tid == 0) valid_out[row] = vld;
}

extern "C" void kernel_launch(void* const* d_in, const int* in_sizes, int n_in,
                              void* d_out, int out_size, void* d_ws, size_t ws_size,
                              hipStream_t stream) {
    const float* time = (const float*)d_in[0];
    const int* mask = (const int*)d_in[1];
    const int* pad_value = (const int*)d_in[2];

    const int B = in_sizes[0] / LROW;

    // d_out layout: pred [B*L] int32, then valid [B] int32 (tuple concat order)
    int* pred = (int*)d_out;
    int* valid_out = pred + (size_t)B * LROW;

    time_greedy_rank_kernel<<<B, THREADS, 0, stream>>>(time, mask, pad_value,
                                                       pred, valid_out);
}